// Round 1
// baseline (466.927 us; speedup 1.0000x reference)
//
#include <hip/hip_runtime.h>
#include <cstdint>
#include <cstddef>

// ---------- types ----------
typedef __attribute__((ext_vector_type(8))) short short8;        // MFMA bf16 A/B frag (4 VGPR)
typedef __attribute__((ext_vector_type(4))) float f32x4;         // MFMA C/D frag
typedef __attribute__((ext_vector_type(4))) unsigned short ushort4_t;

// RNE float->bf16 (finite inputs only)
__device__ __forceinline__ unsigned short f2bf(float f) {
  unsigned u = __float_as_uint(f);
  u += 0x7FFFu + ((u >> 16) & 1u);
  return (unsigned short)(u >> 16);
}

// async global->LDS, 16B per lane. LDS dest must be wave-uniform base (lane*16 implicit).
__device__ __forceinline__ void gload_lds16(const void* g, void* lds) {
  __builtin_amdgcn_global_load_lds((const __attribute__((address_space(1))) void*)g,
                                   (__attribute__((address_space(3))) void*)lds,
                                   16, 0, 0);
}

// ---------- kernel 1: quantize x with per-channel s_a1 (symmetric, qn=-128 qp=127) ----------
__global__ void quant_x_kernel(const float4* __restrict__ x, const float* __restrict__ s_a1,
                               ushort4_t* __restrict__ xq, int n4, int c4mask) {
  const int stride = gridDim.x * blockDim.x;
  for (int i = blockIdx.x * blockDim.x + threadIdx.x; i < n4; i += stride) {
    float4 v = x[i];
    int c = (i & c4mask) << 2;           // channel base (C is pow2)
    float vv[4] = {v.x, v.y, v.z, v.w};
    ushort4_t o;
#pragma unroll
    for (int j = 0; j < 4; ++j) {
      float s = s_a1[c + j];
      float r = vv[j] / s;
      r = fminf(fmaxf(r, -128.f), 127.f);
      o[j] = f2bf(rintf(r) * s);
    }
    xq[i] = o;
  }
}

// ---------- kernel 2: statsq weight quant, one block (256 thr) per output row ----------
__global__ void quant_w_kernel(const float* __restrict__ w, unsigned short* __restrict__ wq,
                               int cols) {
  const int row = blockIdx.x;
  const float* wr = w + (size_t)row * cols;
  float part = 0.f;
  for (int j = threadIdx.x; j < cols; j += blockDim.x) part += fabsf(wr[j]);
#pragma unroll
  for (int o = 32; o > 0; o >>= 1) part += __shfl_down(part, o, 64);
  __shared__ float wsum[4];
  if ((threadIdx.x & 63) == 0) wsum[threadIdx.x >> 6] = part;
  __syncthreads();
  float mean = (wsum[0] + wsum[1] + wsum[2] + wsum[3]) / (float)cols;
  float s = 2.f * mean / sqrtf(127.f);
  unsigned short* wqr = wq + (size_t)row * cols;
  for (int j = threadIdx.x; j < cols; j += blockDim.x) {
    float r = wr[j] / s;
    r = fminf(fmaxf(r, -128.f), 127.f);
    wqr[j] = f2bf(rintf(r) * s);
  }
}

// ---------- GEMM (A: MxK row-major, B: NxK row-major i.e. B^T input) ----------
// m97 structure: 128x128 tile, BK=64, 4 waves (2x2, 64x64 each), global_load_lds w=16,
// T2 st-swizzle applied via pre-swizzled GLOBAL source (linear LDS dest) + swizzled ds_read.
// EPI==0: epilogue = +bias, exact-erf GELU, quant_asym(s2,beta,0,255) -> bf16 Cq
// EPI==1: epilogue = +bias -> f32 Cf
template <int EPI>
__global__ __launch_bounds__(256) void gemm_bt_fused(
    const unsigned short* __restrict__ A, const unsigned short* __restrict__ B,
    const float* __restrict__ bias, const float* __restrict__ s2,
    const float* __restrict__ beta, unsigned short* __restrict__ Cq,
    float* __restrict__ Cf, int N, int K)
{
  constexpr int BK = 64;
  __shared__ __align__(16) unsigned short As[128 * BK];
  __shared__ __align__(16) unsigned short Bs[128 * BK];
  const int tid = threadIdx.x;
  const int w = tid >> 6, ll = tid & 63;
  const int wm = w >> 1, wn = w & 1;
  const long bm = (long)blockIdx.x * 128;
  const long bn = (long)blockIdx.y * 128;

  f32x4 acc[4][4] = {};

  // staging: per wave-call, 64 lanes write 1KB linear LDS (8 rows of 128B).
  // lane ll -> LDS row = rg + (ll>>3), col16 = ll&7.  Source col16 pre-swizzled
  // by (row&7) == (ll>>3) so that reads can XOR-deswizzle (rule #21).
  const int srow = ll >> 3;
  const int scol = ((ll & 7) ^ srow) << 3;  // bf16 elems within row
  const unsigned short* Ag = A + (size_t)bm * K;
  const unsigned short* Bg = B + (size_t)bn * K;

  const int nkt = K / BK;
  for (int kt = 0; kt < nkt; ++kt) {
    __syncthreads();
    const unsigned short* Asrc = Ag + (size_t)kt * BK + scol;
    const unsigned short* Bsrc = Bg + (size_t)kt * BK + scol;
#pragma unroll
    for (int i = 0; i < 4; ++i) {
      int rg = (w * 4 + i) * 8;
      gload_lds16(Asrc + (size_t)(rg + srow) * K, (void*)(As + rg * BK));
      gload_lds16(Bsrc + (size_t)(rg + srow) * K, (void*)(Bs + rg * BK));
    }
    __syncthreads();  // compiler drains vmcnt(0) here (m97 structure)
#pragma unroll
    for (int kk = 0; kk < 2; ++kk) {
      short8 af[4], bf[4];
#pragma unroll
      for (int mi = 0; mi < 4; ++mi) {
        int row = wm * 64 + mi * 16 + (ll & 15);
        int c16 = (kk * 4 + (ll >> 4)) ^ (row & 7);   // de-swizzle on read
        af[mi] = *(const short8*)(As + row * BK + c16 * 8);
      }
#pragma unroll
      for (int ni = 0; ni < 4; ++ni) {
        int row = wn * 64 + ni * 16 + (ll & 15);
        int c16 = (kk * 4 + (ll >> 4)) ^ (row & 7);
        bf[ni] = *(const short8*)(Bs + row * BK + c16 * 8);
      }
#pragma unroll
      for (int mi = 0; mi < 4; ++mi)
#pragma unroll
        for (int ni = 0; ni < 4; ++ni)
          acc[mi][ni] = __builtin_amdgcn_mfma_f32_16x16x32_bf16(af[mi], bf[ni], acc[mi][ni], 0, 0, 0);
    }
  }

  // epilogue — C/D layout: col = lane&15, row = (lane>>4)*4 + reg  [m89-verified]
  const int lr = ll >> 4;
  const int lc = ll & 15;
#pragma unroll
  for (int ni = 0; ni < 4; ++ni) {
    const long col = bn + wn * 64 + ni * 16 + lc;
    const float bv = bias[col];
    float sv = 1.f, bev = 0.f;
    if (EPI == 0) { sv = s2[col]; bev = beta[col]; }
#pragma unroll
    for (int mi = 0; mi < 4; ++mi) {
#pragma unroll
      for (int r = 0; r < 4; ++r) {
        const long rowg = bm + wm * 64 + mi * 16 + lr * 4 + r;
        float v = acc[mi][ni][r] + bv;
        if (EPI == 0) {
          float g = 0.5f * v * (1.f + erff(v * 0.70710678118654752f));  // exact GELU
          float rr = (g - bev) / sv;
          rr = fminf(fmaxf(rr, 0.f), 255.f);   // asym quant, qn=0 qp=255
          float hv = rintf(rr) * sv + bev;
          Cq[rowg * N + col] = f2bf(hv);
        } else {
          Cf[rowg * N + col] = v;
        }
      }
    }
  }
}

// ---------- launch ----------
extern "C" void kernel_launch(void* const* d_in, const int* in_sizes, int n_in,
                              void* d_out, int out_size, void* d_ws, size_t ws_size,
                              hipStream_t stream) {
  const float* x     = (const float*)d_in[0];
  const float* w1    = (const float*)d_in[1];
  const float* b1    = (const float*)d_in[2];
  const float* w2    = (const float*)d_in[3];
  const float* b2    = (const float*)d_in[4];
  const float* s_a1  = (const float*)d_in[5];
  const float* s_a2  = (const float*)d_in[6];
  const float* beta2 = (const float*)d_in[7];
  float* out = (float*)d_out;

  const int C = 1024, H = 4096;
  const int M = in_sizes[0] / C;  // 16384

  // workspace layout (bf16 bit-patterns as u16): xq | wq1 | wq2 | hq  = 184.5 MB
  unsigned short* xq  = (unsigned short*)d_ws;
  unsigned short* wq1 = xq  + (size_t)M * C;
  unsigned short* wq2 = wq1 + (size_t)H * C;
  unsigned short* hq  = wq2 + (size_t)C * H;

  quant_x_kernel<<<2048, 256, 0, stream>>>((const float4*)x, s_a1, (ushort4_t*)xq,
                                           M * C / 4, C / 4 - 1);
  quant_w_kernel<<<H, 256, 0, stream>>>(w1, wq1, C);
  quant_w_kernel<<<C, 256, 0, stream>>>(w2, wq2, H);

  dim3 g1(M / 128, H / 128);  // 128 x 32
  gemm_bt_fused<0><<<g1, 256, 0, stream>>>(xq, wq1, b1, s_a2, beta2, hq, nullptr, H, C);
  dim3 g2(M / 128, C / 128);  // 128 x 8
  gemm_bt_fused<1><<<g2, 256, 0, stream>>>(hq, wq2, b2, nullptr, nullptr, nullptr, out, C, H);
}

// Round 2
// 447.428 us; speedup vs baseline: 1.0436x; 1.0436x over previous
//
#include <hip/hip_runtime.h>
#include <cstdint>
#include <cstddef>

// ---------- types ----------
typedef __attribute__((ext_vector_type(8))) short short8;        // MFMA bf16 A/B frag (4 VGPR)
typedef __attribute__((ext_vector_type(4))) float f32x4;         // MFMA C/D frag
typedef __attribute__((ext_vector_type(4))) unsigned short ushort4_t;

// RNE float->bf16 (finite inputs only)
__device__ __forceinline__ unsigned short f2bf(float f) {
  unsigned u = __float_as_uint(f);
  u += 0x7FFFu + ((u >> 16) & 1u);
  return (unsigned short)(u >> 16);
}

// async global->LDS, 16B per lane. LDS dest must be wave-uniform base (lane*16 implicit).
__device__ __forceinline__ void gload_lds16(const void* g, void* lds) {
  __builtin_amdgcn_global_load_lds((const __attribute__((address_space(1))) void*)g,
                                   (__attribute__((address_space(3))) void*)lds,
                                   16, 0, 0);
}

// Branch-free erf (A&S 7.1.26, abs err <= 1.5e-7), sign folded via bit ops.
// Uses v_rcp_f32 (~1e-7 rel) and native exp; ~15 VALU ops, no divergence.
__device__ __forceinline__ float erf_fast(float v) {
  float x = fabsf(v);
  float t = __builtin_amdgcn_rcpf(fmaf(0.3275911f, x, 1.0f));
  float p = fmaf(1.061405429f, t, -1.453152027f);
  p = fmaf(p, t, 1.421413741f);
  p = fmaf(p, t, -0.284496736f);
  p = fmaf(p, t, 0.254829592f);
  p = p * t;
  float e = fmaf(-p, __expf(-x * x), 1.0f);      // erf(|v|), >= 0
  unsigned s = __float_as_uint(v) & 0x80000000u;
  return __uint_as_float(__float_as_uint(e) | s);
}

// ---------- kernel 1: quantize x with per-channel s_a1 (symmetric, qn=-128 qp=127) ----------
__global__ void quant_x_kernel(const float4* __restrict__ x, const float* __restrict__ s_a1,
                               ushort4_t* __restrict__ xq, int n4, int c4mask) {
  const int stride = gridDim.x * blockDim.x;
  for (int i = blockIdx.x * blockDim.x + threadIdx.x; i < n4; i += stride) {
    float4 v = x[i];
    int c = (i & c4mask) << 2;           // channel base (C is pow2)
    float vv[4] = {v.x, v.y, v.z, v.w};
    ushort4_t o;
#pragma unroll
    for (int j = 0; j < 4; ++j) {
      float s = s_a1[c + j];
      float r = vv[j] / s;
      r = fminf(fmaxf(r, -128.f), 127.f);
      o[j] = f2bf(rintf(r) * s);
    }
    xq[i] = o;
  }
}

// ---------- kernel 2: statsq weight quant, one block (256 thr) per output row ----------
__global__ void quant_w_kernel(const float* __restrict__ w, unsigned short* __restrict__ wq,
                               int cols) {
  const int row = blockIdx.x;
  const float* wr = w + (size_t)row * cols;
  float part = 0.f;
  for (int j = threadIdx.x; j < cols; j += blockDim.x) part += fabsf(wr[j]);
#pragma unroll
  for (int o = 32; o > 0; o >>= 1) part += __shfl_down(part, o, 64);
  __shared__ float wsum[4];
  if ((threadIdx.x & 63) == 0) wsum[threadIdx.x >> 6] = part;
  __syncthreads();
  float mean = (wsum[0] + wsum[1] + wsum[2] + wsum[3]) / (float)cols;
  float s = 2.f * mean / sqrtf(127.f);
  unsigned short* wqr = wq + (size_t)row * cols;
  for (int j = threadIdx.x; j < cols; j += blockDim.x) {
    float r = wr[j] / s;
    r = fminf(fmaxf(r, -128.f), 127.f);
    wqr[j] = f2bf(rintf(r) * s);
  }
}

// ---------- GEMM (A: MxK row-major, B: NxK row-major i.e. B^T input) ----------
// m97 structure: 128x128 tile, BK=64, 4 waves (2x2, 64x64 each), global_load_lds w=16,
// T2 st-swizzle applied via pre-swizzled GLOBAL source (linear LDS dest) + swizzled ds_read.
// EPI==0: epilogue = +bias, branch-free exact-class GELU, quant_asym(s2,beta,0,255) -> bf16 Cq
// EPI==1: epilogue = +bias -> f32 Cf
template <int EPI>
__global__ __launch_bounds__(256) void gemm_bt_fused(
    const unsigned short* __restrict__ A, const unsigned short* __restrict__ B,
    const float* __restrict__ bias, const float* __restrict__ s2,
    const float* __restrict__ beta, unsigned short* __restrict__ Cq,
    float* __restrict__ Cf, int N, int K)
{
  constexpr int BK = 64;
  __shared__ __align__(16) unsigned short As[128 * BK];
  __shared__ __align__(16) unsigned short Bs[128 * BK];
  const int tid = threadIdx.x;
  const int w = tid >> 6, ll = tid & 63;
  const int wm = w >> 1, wn = w & 1;
  const long bm = (long)blockIdx.x * 128;
  const long bn = (long)blockIdx.y * 128;

  f32x4 acc[4][4] = {};

  // staging: per wave-call, 64 lanes write 1KB linear LDS (8 rows of 128B).
  // lane ll -> LDS row = rg + (ll>>3), col16 = ll&7.  Source col16 pre-swizzled
  // by (row&7) == (ll>>3) so that reads can XOR-deswizzle (rule #21).
  const int srow = ll >> 3;
  const int scol = ((ll & 7) ^ srow) << 3;  // bf16 elems within row
  const unsigned short* Ag = A + (size_t)bm * K;
  const unsigned short* Bg = B + (size_t)bn * K;

  const int nkt = K / BK;
  for (int kt = 0; kt < nkt; ++kt) {
    __syncthreads();
    const unsigned short* Asrc = Ag + (size_t)kt * BK + scol;
    const unsigned short* Bsrc = Bg + (size_t)kt * BK + scol;
#pragma unroll
    for (int i = 0; i < 4; ++i) {
      int rg = (w * 4 + i) * 8;
      gload_lds16(Asrc + (size_t)(rg + srow) * K, (void*)(As + rg * BK));
      gload_lds16(Bsrc + (size_t)(rg + srow) * K, (void*)(Bs + rg * BK));
    }
    __syncthreads();  // compiler drains vmcnt(0) here (m97 structure)
#pragma unroll
    for (int kk = 0; kk < 2; ++kk) {
      short8 af[4], bf[4];
#pragma unroll
      for (int mi = 0; mi < 4; ++mi) {
        int row = wm * 64 + mi * 16 + (ll & 15);
        int c16 = (kk * 4 + (ll >> 4)) ^ (row & 7);   // de-swizzle on read
        af[mi] = *(const short8*)(As + row * BK + c16 * 8);
      }
#pragma unroll
      for (int ni = 0; ni < 4; ++ni) {
        int row = wn * 64 + ni * 16 + (ll & 15);
        int c16 = (kk * 4 + (ll >> 4)) ^ (row & 7);
        bf[ni] = *(const short8*)(Bs + row * BK + c16 * 8);
      }
#pragma unroll
      for (int mi = 0; mi < 4; ++mi)
#pragma unroll
        for (int ni = 0; ni < 4; ++ni)
          acc[mi][ni] = __builtin_amdgcn_mfma_f32_16x16x32_bf16(af[mi], bf[ni], acc[mi][ni], 0, 0, 0);
    }
  }

  // epilogue — C/D layout: col = lane&15, row = (lane>>4)*4 + reg  [m89-verified]
  const int lr = ll >> 4;
  const int lc = ll & 15;
#pragma unroll
  for (int ni = 0; ni < 4; ++ni) {
    const long col = bn + wn * 64 + ni * 16 + lc;
    const float bv = bias[col];
    float sv = 1.f, bev = 0.f, inv_sv = 1.f;
    if (EPI == 0) {
      sv = s2[col]; bev = beta[col];
      inv_sv = 1.0f / sv;   // exact div, amortized over 16 outputs
    }
#pragma unroll
    for (int mi = 0; mi < 4; ++mi) {
#pragma unroll
      for (int r = 0; r < 4; ++r) {
        const long rowg = bm + wm * 64 + mi * 16 + lr * 4 + r;
        float v = acc[mi][ni][r] + bv;
        if (EPI == 0) {
          float g = 0.5f * v * (1.f + erf_fast(v * 0.70710678118654752f));
          float rr = (g - bev) * inv_sv;
          rr = fminf(fmaxf(rr, 0.f), 255.f);   // asym quant, qn=0 qp=255
          float hv = fmaf(rintf(rr), sv, bev);
          Cq[rowg * N + col] = f2bf(hv);
        } else {
          Cf[rowg * N + col] = v;
        }
      }
    }
  }
}

// ---------- launch ----------
extern "C" void kernel_launch(void* const* d_in, const int* in_sizes, int n_in,
                              void* d_out, int out_size, void* d_ws, size_t ws_size,
                              hipStream_t stream) {
  const float* x     = (const float*)d_in[0];
  const float* w1    = (const float*)d_in[1];
  const float* b1    = (const float*)d_in[2];
  const float* w2    = (const float*)d_in[3];
  const float* b2    = (const float*)d_in[4];
  const float* s_a1  = (const float*)d_in[5];
  const float* s_a2  = (const float*)d_in[6];
  const float* beta2 = (const float*)d_in[7];
  float* out = (float*)d_out;

  const int C = 1024, H = 4096;
  const int M = in_sizes[0] / C;  // 16384

  // workspace layout (bf16 bit-patterns as u16): xq | wq1 | wq2 | hq  = 184.5 MB
  unsigned short* xq  = (unsigned short*)d_ws;
  unsigned short* wq1 = xq  + (size_t)M * C;
  unsigned short* wq2 = wq1 + (size_t)H * C;
  unsigned short* hq  = wq2 + (size_t)C * H;

  quant_x_kernel<<<2048, 256, 0, stream>>>((const float4*)x, s_a1, (ushort4_t*)xq,
                                           M * C / 4, C / 4 - 1);
  quant_w_kernel<<<H, 256, 0, stream>>>(w1, wq1, C);
  quant_w_kernel<<<C, 256, 0, stream>>>(w2, wq2, H);

  dim3 g1(M / 128, H / 128);  // 128 x 32
  gemm_bt_fused<0><<<g1, 256, 0, stream>>>(xq, wq1, b1, s_a2, beta2, hq, nullptr, H, C);
  dim3 g2(M / 128, C / 128);  // 128 x 8
  gemm_bt_fused<1><<<g2, 256, 0, stream>>>(hq, wq2, b2, nullptr, nullptr, nullptr, out, C, H);
}

// Round 3
// 379.521 us; speedup vs baseline: 1.2303x; 1.1789x over previous
//
#include <hip/hip_runtime.h>
#include <cstdint>
#include <cstddef>

// ---------- types ----------
typedef __attribute__((ext_vector_type(8))) short short8;        // MFMA bf16 A/B frag (4 VGPR)
typedef __attribute__((ext_vector_type(4))) float f32x4;         // MFMA C/D frag
typedef __attribute__((ext_vector_type(4))) unsigned short ushort4_t;

// RNE float->bf16 (finite inputs only)
__device__ __forceinline__ unsigned short f2bf(float f) {
  unsigned u = __float_as_uint(f);
  u += 0x7FFFu + ((u >> 16) & 1u);
  return (unsigned short)(u >> 16);
}

// async global->LDS, 16B per lane. LDS dest is wave-uniform base (+lane*16 implicit).
__device__ __forceinline__ void gload_lds16(const void* g, void* lds) {
  __builtin_amdgcn_global_load_lds((const __attribute__((address_space(1))) void*)g,
                                   (__attribute__((address_space(3))) void*)lds,
                                   16, 0, 0);
}

// Branch-free erf (A&S 7.1.26, abs err <= 1.5e-7), sign folded via bit ops.
__device__ __forceinline__ float erf_fast(float v) {
  float x = fabsf(v);
  float t = __builtin_amdgcn_rcpf(fmaf(0.3275911f, x, 1.0f));
  float p = fmaf(1.061405429f, t, -1.453152027f);
  p = fmaf(p, t, 1.421413741f);
  p = fmaf(p, t, -0.284496736f);
  p = fmaf(p, t, 0.254829592f);
  p = p * t;
  float e = fmaf(-p, __expf(-x * x), 1.0f);      // erf(|v|), >= 0
  unsigned s = __float_as_uint(v) & 0x80000000u;
  return __uint_as_float(__float_as_uint(e) | s);
}

// ---------- kernel 1: quantize x with per-channel s_a1 (symmetric, qn=-128 qp=127) ----------
__global__ void quant_x_kernel(const float4* __restrict__ x, const float* __restrict__ s_a1,
                               ushort4_t* __restrict__ xq, int n4, int c4mask) {
  const int stride = gridDim.x * blockDim.x;
  for (int i = blockIdx.x * blockDim.x + threadIdx.x; i < n4; i += stride) {
    float4 v = x[i];
    int c = (i & c4mask) << 2;           // channel base (C is pow2)
    float vv[4] = {v.x, v.y, v.z, v.w};
    ushort4_t o;
#pragma unroll
    for (int j = 0; j < 4; ++j) {
      float s = s_a1[c + j];
      float r = vv[j] / s;
      r = fminf(fmaxf(r, -128.f), 127.f);
      o[j] = f2bf(rintf(r) * s);
    }
    xq[i] = o;
  }
}

// ---------- kernel 2: statsq weight quant, one block (256 thr) per output row ----------
__global__ void quant_w_kernel(const float* __restrict__ w, unsigned short* __restrict__ wq,
                               int cols) {
  const int row = blockIdx.x;
  const float* wr = w + (size_t)row * cols;
  float part = 0.f;
  for (int j = threadIdx.x; j < cols; j += blockDim.x) part += fabsf(wr[j]);
#pragma unroll
  for (int o = 32; o > 0; o >>= 1) part += __shfl_down(part, o, 64);
  __shared__ float wsum[4];
  if ((threadIdx.x & 63) == 0) wsum[threadIdx.x >> 6] = part;
  __syncthreads();
  float mean = (wsum[0] + wsum[1] + wsum[2] + wsum[3]) / (float)cols;
  float s = 2.f * mean / sqrtf(127.f);
  unsigned short* wqr = wq + (size_t)row * cols;
  for (int j = threadIdx.x; j < cols; j += blockDim.x) {
    float r = wr[j] / s;
    r = fminf(fmaxf(r, -128.f), 127.f);
    wqr[j] = f2bf(rintf(r) * s);
  }
}

// ---------- 8-phase 256x256 GEMM (A: MxK rm, B: NxK rm) ----------
// T3+T4+T5+T2 per the 8-phase template: BK=64, 512 thr (2Mx4N waves, 128x64/wave),
// 2x double-buffered LDS (128KB), per-phase {ds_read quadrant | stage 1 half-tile |
// bar | lgkmcnt(0) | setprio(1) 16xMFMA setprio(0) | bar}, counted vmcnt(6) ONLY at
// tile boundaries (3 half-tiles in flight). Region-safety: each overwrite-issue is
// >=1 barrier after that LDS region's last ds_read (A0 rd ph1, A1 rd ph2, B0 rd ph1,
// B1 rd ph3; issues: B1(t+1)@ph1->other buf, A0(t+2)@ph2, A1(t+2)@ph3, B0(t+2)@ph4).
#define BAR() __builtin_amdgcn_s_barrier()
#define LGKM0() { asm volatile("s_waitcnt lgkmcnt(0)" ::: "memory"); __builtin_amdgcn_sched_barrier(0); }

#define STG(gbase, ldsbuf, h, kt) { \
  _Pragma("unroll") for (int i_ = 0; i_ < 2; ++i_) { \
    const int rb_ = (h) * 128 + (w * 2 + i_) * 8; \
    gload_lds16((gbase) + (size_t)rb_ * K + (size_t)(kt) * 64, (void*)((ldsbuf) + rb_ * 64)); } }

#define LDA_(dst, buf, mh) { \
  _Pragma("unroll") for (int mi_ = 0; mi_ < 4; ++mi_) { \
    dst[mi_][0] = *(const short8*)((buf) + aBase + (mh) * 4096 + mi_ * 1024 + ck0); \
    dst[mi_][1] = *(const short8*)((buf) + aBase + (mh) * 4096 + mi_ * 1024 + ck1); } }

#define LDB_(dst, buf, nh) { \
  _Pragma("unroll") for (int ni_ = 0; ni_ < 2; ++ni_) { \
    dst[ni_][0] = *(const short8*)((buf) + bBase + (nh) * 2048 + ni_ * 1024 + ck0); \
    dst[ni_][1] = *(const short8*)((buf) + bBase + (nh) * 2048 + ni_ * 1024 + ck1); } }

#define MMQ(aR, bR, mh, nh) { \
  _Pragma("unroll") for (int kk_ = 0; kk_ < 2; ++kk_) \
  _Pragma("unroll") for (int mi_ = 0; mi_ < 4; ++mi_) \
  _Pragma("unroll") for (int ni_ = 0; ni_ < 2; ++ni_) \
    acc[(mh) * 4 + mi_][(nh) * 2 + ni_] = __builtin_amdgcn_mfma_f32_16x16x32_bf16( \
        aR[mi_][kk_], bR[ni_][kk_], acc[(mh) * 4 + mi_][(nh) * 2 + ni_], 0, 0, 0); }

template <int EPI>
__global__ __launch_bounds__(512, 2) void gemm_bt_8ph(
    const unsigned short* __restrict__ A, const unsigned short* __restrict__ B,
    const float* __restrict__ bias, const float* __restrict__ s2,
    const float* __restrict__ beta, unsigned short* __restrict__ Cq,
    float* __restrict__ Cf, int N, int K)
{
  __shared__ __align__(16) unsigned short As0[256 * 64];
  __shared__ __align__(16) unsigned short As1[256 * 64];
  __shared__ __align__(16) unsigned short Bs0[256 * 64];
  __shared__ __align__(16) unsigned short Bs1[256 * 64];

  const int tid = threadIdx.x;
  const int w = tid >> 6, ll = tid & 63;
  const int wr = w >> 2, wc = w & 3;
  const long bm = (long)blockIdx.x * 256;
  const long bn = (long)blockIdx.y * 256;

  // staging source (pre-swizzled so linear LDS dest + XOR read = consistent, rule #21)
  const int srow = ll >> 3;
  const int scol = ((ll & 7) ^ srow) << 3;
  const unsigned short* Agl = A + ((size_t)bm + srow) * K + scol;
  const unsigned short* Bgl = B + ((size_t)bn + srow) * K + scol;

  // per-lane ds_read offsets (u16 elems); row&7 == ll&7 for all frag rows
  const int lhi = ll >> 4, llo = ll & 15, l7 = ll & 7;
  const int ck0 = ((0 * 4 + lhi) ^ l7) * 8;
  const int ck1 = ((1 * 4 + lhi) ^ l7) * 8;
  const int aBase = (wr * 128 + llo) * 64;
  const int bBase = (wc * 64 + llo) * 64;

  f32x4 acc[8][4] = {};
  short8 a0[4][2], a1[4][2], b0[2][2], b1[2][2];

  const int nkt = K >> 6;

  // ---- prologue: tile0 (4 half-tiles) + tile1 A0,A1,B0 ----
  STG(Agl, As0, 0, 0); STG(Agl, As0, 1, 0);
  STG(Bgl, Bs0, 0, 0); STG(Bgl, Bs0, 1, 0);
  if (nkt > 1) { STG(Agl, As1, 0, 1); STG(Agl, As1, 1, 1); STG(Bgl, Bs1, 0, 1); }
  if (nkt > 1) { asm volatile("s_waitcnt vmcnt(6)" ::: "memory"); }
  else         { asm volatile("s_waitcnt vmcnt(0)" ::: "memory"); }
  __builtin_amdgcn_sched_barrier(0);
  BAR();

  for (int t = 0; t < nkt; ++t) {
    unsigned short* Asb = (t & 1) ? As1 : As0;
    unsigned short* Bsb = (t & 1) ? Bs1 : Bs0;
    unsigned short* Bsn = (t & 1) ? Bs0 : Bs1;
    const bool i1 = (t + 1 < nkt), i2 = (t + 2 < nkt);

    // phase 1: read A0,B0; stage B1(t+1) -> other buf; compute Q(0,0)
    LDA_(a0, Asb, 0);
    LDB_(b0, Bsb, 0);
    if (i1) STG(Bgl, Bsn, 1, t + 1);
    BAR(); LGKM0();
    __builtin_amdgcn_s_setprio(1); MMQ(a0, b0, 0, 0); __builtin_amdgcn_s_setprio(0);
    BAR();

    // phase 2: read A1; stage A0(t+2) -> cur buf (A0 last read ph1); Q(1,0)
    LDA_(a1, Asb, 1);
    if (i2) STG(Agl, Asb, 0, t + 2);
    BAR(); LGKM0();
    __builtin_amdgcn_s_setprio(1); MMQ(a1, b0, 1, 0); __builtin_amdgcn_s_setprio(0);
    BAR();

    // phase 3: read B1; stage A1(t+2) (A1 last read ph2); Q(1,1)
    LDB_(b1, Bsb, 1);
    if (i2) STG(Agl, Asb, 1, t + 2);
    BAR(); LGKM0();
    __builtin_amdgcn_s_setprio(1); MMQ(a1, b1, 1, 1); __builtin_amdgcn_s_setprio(0);
    BAR();

    // phase 4: stage B0(t+2) (B0 last read ph1); Q(0,1); boundary vmcnt
    if (i2) STG(Bgl, Bsb, 0, t + 2);
    BAR();
    __builtin_amdgcn_s_setprio(1); MMQ(a0, b1, 0, 1); __builtin_amdgcn_s_setprio(0);
    if (i2)      { asm volatile("s_waitcnt vmcnt(6)" ::: "memory"); }
    else if (i1) { asm volatile("s_waitcnt vmcnt(0)" ::: "memory"); }
    __builtin_amdgcn_sched_barrier(0);
    BAR();
  }

  // ---- epilogue; C/D layout: col = lane&15, row = (lane>>4)*4 + reg ----
  const int lr = lhi;
  const int lc = llo;
#pragma unroll
  for (int NI = 0; NI < 4; ++NI) {
    const long col = bn + wc * 64 + NI * 16 + lc;
    const float bv = bias[col];
    float sv = 1.f, bev = 0.f, inv = 1.f;
    if (EPI == 0) { sv = s2[col]; bev = beta[col]; inv = 1.0f / sv; }
#pragma unroll
    for (int MI = 0; MI < 8; ++MI) {
#pragma unroll
      for (int r = 0; r < 4; ++r) {
        const size_t rowg = (size_t)(bm + wr * 128 + MI * 16 + lr * 4 + r);
        float v = acc[MI][NI][r] + bv;
        if (EPI == 0) {
          float g = 0.5f * v * (1.f + erf_fast(v * 0.70710678118654752f));
          float rr = (g - bev) * inv;
          rr = fminf(fmaxf(rr, 0.f), 255.f);
          Cq[rowg * N + col] = f2bf(fmaf(rintf(rr), sv, bev));
        } else {
          Cf[rowg * N + col] = v;
        }
      }
    }
  }
}

// ---------- launch ----------
extern "C" void kernel_launch(void* const* d_in, const int* in_sizes, int n_in,
                              void* d_out, int out_size, void* d_ws, size_t ws_size,
                              hipStream_t stream) {
  const float* x     = (const float*)d_in[0];
  const float* w1    = (const float*)d_in[1];
  const float* b1    = (const float*)d_in[2];
  const float* w2    = (const float*)d_in[3];
  const float* b2    = (const float*)d_in[4];
  const float* s_a1  = (const float*)d_in[5];
  const float* s_a2  = (const float*)d_in[6];
  const float* beta2 = (const float*)d_in[7];
  float* out = (float*)d_out;

  const int C = 1024, H = 4096;
  const int M = in_sizes[0] / C;  // 16384

  // workspace layout (bf16 bit-patterns as u16): xq | wq1 | wq2 | hq
  unsigned short* xq  = (unsigned short*)d_ws;
  unsigned short* wq1 = xq  + (size_t)M * C;
  unsigned short* wq2 = wq1 + (size_t)H * C;
  unsigned short* hq  = wq2 + (size_t)C * H;

  quant_x_kernel<<<2048, 256, 0, stream>>>((const float4*)x, s_a1, (ushort4_t*)xq,
                                           M * C / 4, C / 4 - 1);
  quant_w_kernel<<<H, 256, 0, stream>>>(w1, wq1, C);
  quant_w_kernel<<<C, 256, 0, stream>>>(w2, wq2, H);

  dim3 g1(M / 256, H / 256);  // 64 x 16
  gemm_bt_8ph<0><<<g1, 512, 0, stream>>>(xq, wq1, b1, s_a2, beta2, hq, nullptr, H, C);
  dim3 g2(M / 256, C / 256);  // 64 x 4
  gemm_bt_8ph<1><<<g2, 512, 0, stream>>>(hq, wq2, b2, nullptr, nullptr, nullptr, out, C, H);
}

// Round 4
// 367.031 us; speedup vs baseline: 1.2722x; 1.0340x over previous
//
#include <hip/hip_runtime.h>
#include <cstdint>
#include <cstddef>

// ---------- types ----------
typedef __attribute__((ext_vector_type(8))) short short8;        // MFMA bf16 A/B frag (4 VGPR)
typedef __attribute__((ext_vector_type(4))) float f32x4;         // MFMA C/D frag
typedef __attribute__((ext_vector_type(4))) unsigned short ushort4_t;

// RNE float->bf16 (finite inputs only)
__device__ __forceinline__ unsigned short f2bf(float f) {
  unsigned u = __float_as_uint(f);
  u += 0x7FFFu + ((u >> 16) & 1u);
  return (unsigned short)(u >> 16);
}

// async global->LDS, 16B per lane. LDS dest is wave-uniform base (+lane*16 implicit).
__device__ __forceinline__ void gload_lds16(const void* g, void* lds) {
  __builtin_amdgcn_global_load_lds((const __attribute__((address_space(1))) void*)g,
                                   (__attribute__((address_space(3))) void*)lds,
                                   16, 0, 0);
}

// Branch-free erf (A&S 7.1.26, abs err <= 1.5e-7), sign folded via bit ops.
__device__ __forceinline__ float erf_fast(float v) {
  float x = fabsf(v);
  float t = __builtin_amdgcn_rcpf(fmaf(0.3275911f, x, 1.0f));
  float p = fmaf(1.061405429f, t, -1.453152027f);
  p = fmaf(p, t, 1.421413741f);
  p = fmaf(p, t, -0.284496736f);
  p = fmaf(p, t, 0.254829592f);
  p = p * t;
  float e = fmaf(-p, __expf(-x * x), 1.0f);      // erf(|v|), >= 0
  unsigned s = __float_as_uint(v) & 0x80000000u;
  return __uint_as_float(__float_as_uint(e) | s);
}

// ---------- kernel 1: quantize x with per-channel s_a1 (symmetric, qn=-128 qp=127) ----------
__global__ void quant_x_kernel(const float4* __restrict__ x, const float* __restrict__ s_a1,
                               ushort4_t* __restrict__ xq, int n4, int c4mask) {
  const int stride = gridDim.x * blockDim.x;
  for (int i = blockIdx.x * blockDim.x + threadIdx.x; i < n4; i += stride) {
    float4 v = x[i];
    int c = (i & c4mask) << 2;           // channel base (C is pow2)
    float vv[4] = {v.x, v.y, v.z, v.w};
    ushort4_t o;
#pragma unroll
    for (int j = 0; j < 4; ++j) {
      float s = s_a1[c + j];
      float r = vv[j] / s;
      r = fminf(fmaxf(r, -128.f), 127.f);
      o[j] = f2bf(rintf(r) * s);
    }
    xq[i] = o;
  }
}

// ---------- kernel 2: statsq weight quant, one block (256 thr) per output row ----------
__global__ void quant_w_kernel(const float* __restrict__ w, unsigned short* __restrict__ wq,
                               int cols) {
  const int row = blockIdx.x;
  const float* wr = w + (size_t)row * cols;
  float part = 0.f;
  for (int j = threadIdx.x; j < cols; j += blockDim.x) part += fabsf(wr[j]);
#pragma unroll
  for (int o = 32; o > 0; o >>= 1) part += __shfl_down(part, o, 64);
  __shared__ float wsum[4];
  if ((threadIdx.x & 63) == 0) wsum[threadIdx.x >> 6] = part;
  __syncthreads();
  float mean = (wsum[0] + wsum[1] + wsum[2] + wsum[3]) / (float)cols;
  float s = 2.f * mean / sqrtf(127.f);
  unsigned short* wqr = wq + (size_t)row * cols;
  for (int j = threadIdx.x; j < cols; j += blockDim.x) {
    float r = wr[j] / s;
    r = fminf(fmaxf(r, -128.f), 127.f);
    wqr[j] = f2bf(rintf(r) * s);
  }
}

// ---------- pipelined 256x256 GEMM (A: MxK rm, B: NxK rm) ----------
// One barrier per K-tile; counted lgkm waits overlap ds_read drain with MFMA
// quadrants; next-tile a0/b0 fragments pre-read into the SAME registers after
// their last use (register-neutral). Stage->read proof chain per tile t:
//   STG(t+1) issued in tile t-1 body (post-BAR)
//   VMC0 in tile t  (per-wave: own stages landed)
//   BAR  in tile t  (block-wide collection)
//   reads of tile t+1 data issued after that BAR.
// cur-buffer overwrite safety: each wave's cur reads drained at LGKM(0) before
// Q3; BAR collects; STG(t+2)->cur issued post-BAR only.
#define BAR() __builtin_amdgcn_s_barrier()
#define SB() __builtin_amdgcn_sched_barrier(0)
#define LGKM(n) { asm volatile("s_waitcnt lgkmcnt(" #n ")" ::: "memory"); SB(); }
#define VMC0() { asm volatile("s_waitcnt vmcnt(0)" ::: "memory"); SB(); }
#define PRIO1() __builtin_amdgcn_s_setprio(1)
#define PRIO0() __builtin_amdgcn_s_setprio(0)

#define STG(gbase, ldsbuf, h, kt) { \
  _Pragma("unroll") for (int i_ = 0; i_ < 2; ++i_) { \
    const int rb_ = (h) * 128 + (w * 2 + i_) * 8; \
    gload_lds16((gbase) + (size_t)rb_ * K + (size_t)(kt) * 64, (void*)((ldsbuf) + rb_ * 64)); } }

#define LDA_(dst, buf, mh) { \
  _Pragma("unroll") for (int mi_ = 0; mi_ < 4; ++mi_) { \
    dst[mi_][0] = *(const short8*)((buf) + aBase + (mh) * 4096 + mi_ * 1024 + ck0); \
    dst[mi_][1] = *(const short8*)((buf) + aBase + (mh) * 4096 + mi_ * 1024 + ck1); } }

#define LDB_(dst, buf, nh) { \
  _Pragma("unroll") for (int ni_ = 0; ni_ < 2; ++ni_) { \
    dst[ni_][0] = *(const short8*)((buf) + bBase + (nh) * 2048 + ni_ * 1024 + ck0); \
    dst[ni_][1] = *(const short8*)((buf) + bBase + (nh) * 2048 + ni_ * 1024 + ck1); } }

#define MMQ(aR, bR, mh, nh) { \
  _Pragma("unroll") for (int kk_ = 0; kk_ < 2; ++kk_) \
  _Pragma("unroll") for (int mi_ = 0; mi_ < 4; ++mi_) \
  _Pragma("unroll") for (int ni_ = 0; ni_ < 2; ++ni_) \
    acc[(mh) * 4 + mi_][(nh) * 2 + ni_] = __builtin_amdgcn_mfma_f32_16x16x32_bf16( \
        aR[mi_][kk_], bR[ni_][kk_], acc[(mh) * 4 + mi_][(nh) * 2 + ni_], 0, 0, 0); }

template <int EPI>
__global__ __launch_bounds__(512, 2) void gemm_bt_pl(
    const unsigned short* __restrict__ A, const unsigned short* __restrict__ B,
    const float* __restrict__ bias, const float* __restrict__ s2,
    const float* __restrict__ beta, unsigned short* __restrict__ Cq,
    float* __restrict__ Cf, int N, int K)
{
  __shared__ __align__(16) unsigned short As0[256 * 64];
  __shared__ __align__(16) unsigned short As1[256 * 64];
  __shared__ __align__(16) unsigned short Bs0[256 * 64];
  __shared__ __align__(16) unsigned short Bs1[256 * 64];

  const int tid = threadIdx.x;
  const int w = tid >> 6, ll = tid & 63;
  const int wr = w >> 2, wc = w & 3;
  const long bm = (long)blockIdx.x * 256;
  const long bn = (long)blockIdx.y * 256;

  // staging source (pre-swizzled so linear LDS dest + XOR read = consistent, rule #21)
  const int srow = ll >> 3;
  const int scol = ((ll & 7) ^ srow) << 3;
  const unsigned short* Agl = A + ((size_t)bm + srow) * K + scol;
  const unsigned short* Bgl = B + ((size_t)bn + srow) * K + scol;

  // per-lane ds_read offsets (u16 elems)
  const int lhi = ll >> 4, llo = ll & 15, l7 = ll & 7;
  const int ck0 = ((0 * 4 + lhi) ^ l7) * 8;
  const int ck1 = ((1 * 4 + lhi) ^ l7) * 8;
  const int aBase = (wr * 128 + llo) * 64;
  const int bBase = (wc * 64 + llo) * 64;

  f32x4 acc[8][4] = {};
  short8 a0[4][2], a1[4][2], b0[2][2], b1[2][2];

  const int nkt = K >> 6;   // >= 2 for all shapes here

  // ---- prologue: stage tile0 -> buf0, tile1 -> buf1; prove tile0; pre-read R1(0) ----
  STG(Agl, As0, 0, 0); STG(Agl, As0, 1, 0);
  STG(Bgl, Bs0, 0, 0); STG(Bgl, Bs0, 1, 0);
  STG(Agl, As1, 0, 1); STG(Agl, As1, 1, 1);
  STG(Bgl, Bs1, 0, 1); STG(Bgl, Bs1, 1, 1);
  asm volatile("s_waitcnt vmcnt(8)" ::: "memory"); SB();
  BAR();
  LDA_(a0, As0, 0);                 // 8 reads  (tile0 quadrant A0)
  LDB_(b0, Bs0, 0);                 // 4 reads  (tile0 quadrant B0)

  for (int t = 0; t < nkt; ++t) {
    unsigned short* Asb = (t & 1) ? As1 : As0;
    unsigned short* Bsb = (t & 1) ? Bs1 : Bs0;
    unsigned short* Asn = (t & 1) ? As0 : As1;
    unsigned short* Bsn = (t & 1) ? Bs0 : Bs1;
    const bool i1 = (t + 1 < nkt), i2 = (t + 2 < nkt);

    // entry invariant: lgkm outstanding = 12 (a0,b0 of tile t)
    LDB_(b1, Bsb, 1);                                   // +4 -> 16
    LGKM(4);                                            // a0,b0 ready; b1 in flight
    PRIO1(); MMQ(a0, b0, 0, 0); PRIO0();                // Q1
    LDA_(a1, Asb, 1);                                   // +8 -> <=12
    LGKM(8);                                            // b1 ready; a1 in flight
    PRIO1(); MMQ(a0, b1, 0, 1); PRIO0();                // Q2
    LGKM(0);                                            // a1 ready; all cur reads drained
    PRIO1(); MMQ(a1, b0, 1, 0); PRIO0();                // Q3
    VMC0();                                             // tile t+1 stages landed (per-wave)
    BAR();                                              // block-wide: t+1 proven, cur free
    if (i2) {
      STG(Agl, Asb, 0, t + 2); STG(Agl, Asb, 1, t + 2);
      STG(Bgl, Bsb, 0, t + 2); STG(Bgl, Bsb, 1, t + 2);
    }
    if (i1) {
      LDA_(a0, Asn, 0);                                 // next-tile R1 into freed regs
      LDB_(b0, Bsn, 0);
    }
    PRIO1(); MMQ(a1, b1, 1, 1); PRIO0();                // Q4 overlaps R1' drain + stage issue
  }

  // ---- epilogue; C/D layout: col = lane&15, row = (lane>>4)*4 + reg ----
  const int lr = lhi;
  const int lc = llo;
#pragma unroll
  for (int NI = 0; NI < 4; ++NI) {
    const long col = bn + wc * 64 + NI * 16 + lc;
    const float bv = bias[col];
    float sv = 1.f, bev = 0.f, inv = 1.f;
    if (EPI == 0) { sv = s2[col]; bev = beta[col]; inv = 1.0f / sv; }
#pragma unroll
    for (int MI = 0; MI < 8; ++MI) {
#pragma unroll
      for (int r = 0; r < 4; ++r) {
        const size_t rowg = (size_t)(bm + wr * 128 + MI * 16 + lr * 4 + r);
        float v = acc[MI][NI][r] + bv;
        if (EPI == 0) {
          float g = 0.5f * v * (1.f + erf_fast(v * 0.70710678118654752f));
          float rr = (g - bev) * inv;
          rr = fminf(fmaxf(rr, 0.f), 255.f);
          Cq[rowg * N + col] = f2bf(fmaf(rintf(rr), sv, bev));
        } else {
          Cf[rowg * N + col] = v;
        }
      }
    }
  }
}

// ---------- launch ----------
extern "C" void kernel_launch(void* const* d_in, const int* in_sizes, int n_in,
                              void* d_out, int out_size, void* d_ws, size_t ws_size,
                              hipStream_t stream) {
  const float* x     = (const float*)d_in[0];
  const float* w1    = (const float*)d_in[1];
  const float* b1    = (const float*)d_in[2];
  const float* w2    = (const float*)d_in[3];
  const float* b2    = (const float*)d_in[4];
  const float* s_a1  = (const float*)d_in[5];
  const float* s_a2  = (const float*)d_in[6];
  const float* beta2 = (const float*)d_in[7];
  float* out = (float*)d_out;

  const int C = 1024, H = 4096;
  const int M = in_sizes[0] / C;  // 16384

  // workspace layout (bf16 bit-patterns as u16): xq | wq1 | wq2 | hq
  unsigned short* xq  = (unsigned short*)d_ws;
  unsigned short* wq1 = xq  + (size_t)M * C;
  unsigned short* wq2 = wq1 + (size_t)H * C;
  unsigned short* hq  = wq2 + (size_t)C * H;

  quant_x_kernel<<<2048, 256, 0, stream>>>((const float4*)x, s_a1, (ushort4_t*)xq,
                                           M * C / 4, C / 4 - 1);
  quant_w_kernel<<<H, 256, 0, stream>>>(w1, wq1, C);
  quant_w_kernel<<<C, 256, 0, stream>>>(w2, wq2, H);

  dim3 g1(M / 256, H / 256);  // 64 x 16
  gemm_bt_pl<0><<<g1, 512, 0, stream>>>(xq, wq1, b1, s_a2, beta2, hq, nullptr, H, C);
  dim3 g2(M / 256, C / 256);  // 64 x 4
  gemm_bt_pl<1><<<g2, 512, 0, stream>>>(hq, wq2, b2, nullptr, nullptr, nullptr, out, C, H);
}